// Round 1
// baseline (492.670 us; speedup 1.0000x reference)
//
#include <hip/hip_runtime.h>

// ---------------------------------------------------------------------------
// SpatialAwareSelfAttention  (B=16, H=W=56, C=512, heads=8, window=4x4)
//
// Round 4: A-in-registers head-loop fused kernel.
//   k_fused: grid (784) x 256 thr. Each wave holds its 16 tokens' full
//   512-wide A row-panel in 64 VGPRs (loaded from XW ONCE — kills the 8x
//   per-head XW re-fetch). Loop over 8 heads: stream the head's 192x512
//   weight panel (L2-resident) through a double-buffered BK=64 LDS chunk
//   (one barrier per chunk, loads in flight across it), XOR-swizzled
//   (linear gl2lds dest + inverse-swizzled global src + swizzled ds_read)
//   so ds_read_b128 is conflict-free. Per-head attention epilogue is the
//   previously verified per-wave in-register-softmax code, its LDS region
//   aliasing the staging double-buffer (48KB total -> 3 blocks/CU).
//   k_gemm_proj / k_gemm512 / prep kernels unchanged.
// ---------------------------------------------------------------------------

using bf16x8 = __attribute__((ext_vector_type(8))) short;
using f32x4  = __attribute__((ext_vector_type(4))) float;

#define SCALE 0.044194173824159216f   // 512^-0.5 (full C, per reference)

__device__ __forceinline__ unsigned short f2bf(float f) {
    union { float f; unsigned u; } v; v.f = f;
    unsigned u = v.u;
    return (unsigned short)((u + 0x7fffu + ((u >> 16) & 1u)) >> 16);
}

__device__ __forceinline__ void gl2lds16(const unsigned short* g, unsigned short* l) {
    __builtin_amdgcn_global_load_lds(
        (const __attribute__((address_space(1))) void*)g,
        (__attribute__((address_space(3))) void*)l, 16, 0, 0);
}

// ---- K0a: weight conversion/repack ----------------------------------------
__global__ void k_prep_weights(const float* __restrict__ wqkv_h,
                               const float* __restrict__ wqkv_l,
                               const float* __restrict__ wproj,
                               unsigned short* __restrict__ WH,
                               unsigned short* __restrict__ WLV,
                               unsigned short* __restrict__ WP1,
                               unsigned short* __restrict__ WP2) {
    int i = blockIdx.x * 256 + threadIdx.x;
    if (i < 786432) {
        WH[i] = f2bf(wqkv_h[i]);              // [1536][512] row-major
    } else {
        int j = i - 786432;
        int r = j >> 18;
        int t = j & 262143;
        int n = t >> 9, k = t & 511;
        if (r == 0)      WLV[t] = f2bf(wqkv_l[(1024 + n) * 512 + k]); // v-rows
        else if (r == 1) WP1[t] = f2bf(wproj[n * 1024 + k]);
        else             WP2[t] = f2bf(wproj[n * 1024 + 512 + k]);
    }
}

// ---- K0b: window partition + pooling (float4 / ushort4) -------------------
__global__ void k_window_pool(const float* __restrict__ x,
                              unsigned short* __restrict__ XW,
                              unsigned short* __restrict__ XAVG) {
    int win = blockIdx.x * 2 + (threadIdx.x >> 7);
    int g = threadIdx.x & 127;
    int c = g * 4;
    int b = win / 196, rem = win % 196, wh = rem / 14, ww = rem % 14;
    float4 s = {0.f, 0.f, 0.f, 0.f};
    #pragma unroll
    for (int t = 0; t < 16; ++t) {
        int row = (b * 56 + wh * 4 + (t >> 2)) * 56 + ww * 4 + (t & 3);
        float4 v = *(const float4*)&x[(size_t)row * 512 + c];
        uint2 pk;
        pk.x = (unsigned)f2bf(v.x) | ((unsigned)f2bf(v.y) << 16);
        pk.y = (unsigned)f2bf(v.z) | ((unsigned)f2bf(v.w) << 16);
        *(uint2*)&XW[(size_t)(win * 16 + t) * 512 + c] = pk;
        s.x += v.x; s.y += v.y; s.z += v.z; s.w += v.w;
    }
    uint2 pa;
    pa.x = (unsigned)f2bf(s.x * 0.0625f) | ((unsigned)f2bf(s.y * 0.0625f) << 16);
    pa.y = (unsigned)f2bf(s.z * 0.0625f) | ((unsigned)f2bf(s.w * 0.0625f) << 16);
    *(uint2*)&XAVG[(size_t)win * 512 + c] = pa;
}

// ---- K1: small K=512 GEMM C = A @ B^T, wave tile 16 x (NT*16) -------------
template <int NT>
__global__ void k_gemm512(const unsigned short* __restrict__ A,
                          const unsigned short* __restrict__ Bw,
                          unsigned short* __restrict__ outB,
                          float* __restrict__ outF,
                          const float* __restrict__ bias) {
    int wave = threadIdx.x >> 6, lane = threadIdx.x & 63;
    int quad = lane >> 4, l16 = lane & 15;
    int m0 = blockIdx.x * 64 + wave * 16;
    int n0 = blockIdx.y * (NT * 16);
    f32x4 acc[NT] = {};
    const unsigned short* arow = A + (size_t)(m0 + l16) * 512 + quad * 8;
    for (int kk = 0; kk < 16; ++kk) {
        bf16x8 a = *(const bf16x8*)(arow + kk * 32);
        #pragma unroll
        for (int nt = 0; nt < NT; ++nt) {
            bf16x8 b = *(const bf16x8*)(Bw + (size_t)(n0 + nt * 16 + l16) * 512 + kk * 32 + quad * 8);
            acc[nt] = __builtin_amdgcn_mfma_f32_16x16x32_bf16(a, b, acc[nt], 0, 0, 0);
        }
    }
    #pragma unroll
    for (int nt = 0; nt < NT; ++nt) {
        int col = n0 + nt * 16 + l16;
        float bv = (bias != nullptr) ? bias[col] : 0.f;
        #pragma unroll
        for (int r = 0; r < 4; ++r) {
            int row = m0 + quad * 4 + r;
            if (outF != nullptr) outF[(size_t)row * 512 + col] = acc[nt][r] + bv;
            else                 outB[(size_t)row * 512 + col] = f2bf(acc[nt][r]);
        }
    }
}

// ---- K2: fused qkv GEMM + window attention, A-in-regs, head loop ----------
// grid (784): blockIdx.x = 64-token block (4 windows). Wave w owns window w.
// Per wave: A rows (16 tok x 512 K) live in 16 bf16x8 regs for the whole
// kernel. For each head h: stream WH rows [q|k|v of head h] (192x512) in 8
// BK=64 chunks through a double-buffered swizzled LDS tile; MFMA into
// acc[12]; then the per-wave attention epilogue (LDS region aliases bufs).
__global__ void __launch_bounds__(256, 3) k_fused(const unsigned short* __restrict__ XW,
                                                  const unsigned short* __restrict__ WH,
                                                  unsigned short* __restrict__ XH) {
    __shared__ __align__(16) char smem[49152];
    unsigned short* Bbuf[2] = { (unsigned short*)smem,              // [192][64] chunk, 24576 B
                                (unsigned short*)(smem + 24576) };
    // attention region (aliases the staging double-buffer, used between
    // chunk-loop completion and the end-of-head barrier):
    unsigned short* qs  = (unsigned short*)smem;             // [64][72]   9216 B
    unsigned short* ks  = (unsigned short*)(smem + 9216);    // [64][72]   9216 B
    unsigned short* vts = (unsigned short*)(smem + 18432);   // [64][88]  11264 B (ch x tok)
    unsigned short* Ps  = (unsigned short*)(smem + 29696);   // [4][16][32] 4096 B

    const int wave = threadIdx.x >> 6, lane = threadIdx.x & 63;
    const int quad = lane >> 4, l16 = lane & 15;
    const int m0   = blockIdx.x * 64;
    const int t0   = wave * 16;

    // ---- A panel: 16 tokens x 512 in registers (64 VGPR), loaded ONCE -----
    bf16x8 a_reg[16];
    {
        const unsigned short* arow = XW + (size_t)(m0 + t0 + l16) * 512 + quad * 8;
        #pragma unroll
        for (int kk = 0; kk < 16; ++kk)
            a_reg[kk] = *(const bf16x8*)(arow + kk * 32);
    }

    // ---- B staging slot map (rule #21: linear LDS dest, inverse-swizzled
    //      global source; reads apply unit ^= (row&7)). 6 x 16B per thread
    //      per chunk. Chunk LDS layout: row n (0..191) x 64 shorts, row
    //      stride 128B; 16B-unit u holds global unit u^(n&7).
    int bofs[6];   // short-offset into WH for head 0, chunk 0
    #pragma unroll
    for (int i = 0; i < 6; ++i) {
        int slot = (wave * 6 + i) * 64 + lane;    // linear 16B-unit 0..1535
        int n = slot >> 3;                         // qkv row 0..191 (s-major)
        int gu = (lane & 7) ^ (n & 7);             // inverse-swizzled src unit
        bofs[i] = ((n >> 6) * 512 + (n & 63)) * 512 + gu * 8;
    }

    for (int h = 0; h < 8; ++h) {
        const unsigned short* Bh = WH + h * 32768;   // + head*64 rows (shorts)

        // prologue: stage chunk 0 -> buf0
        #pragma unroll
        for (int i = 0; i < 6; ++i)
            gl2lds16(Bh + bofs[i], Bbuf[0] + (wave * 6 + i) * 512);
        __syncthreads();

        f32x4 acc[12] = {};   // wave tile: 16 tok x 192 cols (q|k|v)

        #pragma unroll
        for (int c = 0; c < 8; ++c) {
            unsigned short* cur = Bbuf[c & 1];
            if (c < 7) {
                unsigned short* nxt = Bbuf[(c + 1) & 1];
                #pragma unroll
                for (int i = 0; i < 6; ++i)
                    gl2lds16(Bh + bofs[i] + (c + 1) * 64, nxt + (wave * 6 + i) * 512);
            }
            #pragma unroll
            for (int kk = 0; kk < 2; ++kk) {
                bf16x8 a = a_reg[c * 2 + kk];
                int su = ((kk * 4 + quad) ^ (l16 & 7)) * 8;   // swizzled unit
                #pragma unroll
                for (int j = 0; j < 12; ++j) {
                    bf16x8 b = *(const bf16x8*)&cur[(j * 16 + l16) * 64 + su];
                    acc[j] = __builtin_amdgcn_mfma_f32_16x16x32_bf16(a, b, acc[j], 0, 0, 0);
                }
            }
            __syncthreads();   // drains vmcnt (next chunk landed) + all waves
                               // done reading cur (safe to overwrite next iter)
        }

        // ---- scatter q/k/v^T into attention LDS (aliases staging bufs) ----
        #pragma unroll
        for (int j = 0; j < 12; ++j) {
            #pragma unroll
            for (int r = 0; r < 4; ++r) {
                int tok = wave * 16 + quad * 4 + r;   // block-local token
                unsigned short hv = f2bf(acc[j][r]);
                if (j < 4)        qs[tok * 72 + j * 16 + l16] = hv;
                else if (j < 8)   ks[tok * 72 + (j - 4) * 16 + l16] = hv;
                else              vts[((j - 8) * 16 + l16) * 88 + tok] = hv;
            }
        }
        // re-zero pads each head (staging clobbered them):
        // vts token-cols 64..79 (read by wave 3's PV), Ps cols 16..31.
        if (wave == 3) {
            #pragma unroll
            for (int i = 0; i < 16; ++i) vts[lane * 88 + 64 + i] = 0;
        }
        {
            int prow = lane >> 2, pc = 16 + (lane & 3) * 4;
            #pragma unroll
            for (int i = 0; i < 4; ++i) Ps[wave * 512 + prow * 32 + pc + i] = 0;
        }
        // no barrier: each wave reads only its own window's qs/ks/vts/Ps rows
        // (PV's K-padding taps neighbor region but P=0 there).

        // ---- S = (q @ k^T) * scale ----------------------------------------
        f32x4 sacc = {};
        {
            bf16x8 a0 = *(const bf16x8*)&qs[(t0 + l16) * 72 + quad * 8];
            bf16x8 b0 = *(const bf16x8*)&ks[(t0 + l16) * 72 + quad * 8];
            sacc = __builtin_amdgcn_mfma_f32_16x16x32_bf16(a0, b0, sacc, 0, 0, 0);
            bf16x8 a1 = *(const bf16x8*)&qs[(t0 + l16) * 72 + 32 + quad * 8];
            bf16x8 b1 = *(const bf16x8*)&ks[(t0 + l16) * 72 + 32 + quad * 8];
            sacc = __builtin_amdgcn_mfma_f32_16x16x32_bf16(a1, b1, sacc, 0, 0, 0);
        }
        // ---- in-register softmax: row r lives across the quad's 16 lanes --
        float p[4];
        #pragma unroll
        for (int r = 0; r < 4; ++r) {
            float v = sacc[r] * SCALE;
            float m = v;
            m = fmaxf(m, __shfl_xor(m, 1));
            m = fmaxf(m, __shfl_xor(m, 2));
            m = fmaxf(m, __shfl_xor(m, 4));
            m = fmaxf(m, __shfl_xor(m, 8));
            float e = __expf(v - m);
            float s = e;
            s += __shfl_xor(s, 1);
            s += __shfl_xor(s, 2);
            s += __shfl_xor(s, 4);
            s += __shfl_xor(s, 8);
            p[r] = e / s;
        }
        #pragma unroll
        for (int r = 0; r < 4; ++r)
            Ps[wave * 512 + (quad * 4 + r) * 32 + l16] = f2bf(p[r]);

        // ---- y = P @ v (K=16 padded to 32; pad-P is zero) -----------------
        bf16x8 pa = *(const bf16x8*)&Ps[wave * 512 + l16 * 32 + quad * 8];
        #pragma unroll
        for (int nt = 0; nt < 4; ++nt) {
            f32x4 y = {};
            bf16x8 bv = *(const bf16x8*)&vts[(nt * 16 + l16) * 88 + t0 + quad * 8];
            y = __builtin_amdgcn_mfma_f32_16x16x32_bf16(pa, bv, y, 0, 0, 0);
            #pragma unroll
            for (int r = 0; r < 4; ++r)
                XH[(size_t)(m0 + t0 + quad * 4 + r) * 512 + h * 64 + nt * 16 + l16] = f2bf(y[r]);
        }

        __syncthreads();   // all waves' attention LDS reads done before the
                           // next head's staging overwrites the region
    }
}

// ---- K3: out = XH @ WP1^T + G[win], 64x128 tiles, scatter epilogue --------
// grid (784, 4)
__global__ void __launch_bounds__(256, 4) k_gemm_proj(const unsigned short* __restrict__ XH,
                                                      const unsigned short* __restrict__ WP1,
                                                      const float* __restrict__ G,
                                                      float* __restrict__ out) {
    __shared__ __align__(16) unsigned short As[2048];   // [64][32]   4096 B
    __shared__ __align__(16) unsigned short Bs[4096];   // [128][32]  8192 B

    const int wave = threadIdx.x >> 6, lane = threadIdx.x & 63;
    const int quad = lane >> 4, l16 = lane & 15;
    const int m0 = blockIdx.x * 64, n0 = blockIdx.y * 128;

    const unsigned short* ap;
    {
        int q = wave * 64 + lane;
        ap = XH + (size_t)(m0 + (q >> 2)) * 512 + (q & 3) * 8;
    }
    const unsigned short* bp[2];
    #pragma unroll
    for (int i = 0; i < 2; ++i) {
        int q = (wave * 2 + i) * 64 + lane;
        bp[i] = WP1 + (size_t)(n0 + (q >> 2)) * 512 + (q & 3) * 8;
    }

    f32x4 acc[8] = {};    // wave tile: rows wave*16..+15, cols n0..n0+127

    for (int it = 0; it < 16; ++it) {
        gl2lds16(ap + it * 32, As + wave * 512);
        #pragma unroll
        for (int i = 0; i < 2; ++i)
            gl2lds16(bp[i] + it * 32, Bs + (wave * 2 + i) * 512);
        __syncthreads();
        bf16x8 af = *(const bf16x8*)&As[(wave * 16 + l16) * 32 + quad * 8];
        #pragma unroll
        for (int j = 0; j < 8; ++j) {
            bf16x8 b = *(const bf16x8*)&Bs[(j * 16 + l16) * 32 + quad * 8];
            acc[j] = __builtin_amdgcn_mfma_f32_16x16x32_bf16(af, b, acc[j], 0, 0, 0);
        }
        __syncthreads();
    }

    int win = blockIdx.x * 4 + wave;
    int bb = win / 196, rem = win % 196;
    int wh = rem / 14, ww = rem % 14;
    #pragma unroll
    for (int r = 0; r < 4; ++r) {
        int tok = quad * 4 + r;
        int orow = (bb * 56 + wh * 4 + (tok >> 2)) * 56 + ww * 4 + (tok & 3);
        #pragma unroll
        for (int j = 0; j < 8; ++j) {
            int ncol = n0 + j * 16 + l16;
            out[(size_t)orow * 512 + ncol] = acc[j][r] + G[(size_t)win * 512 + ncol];
        }
    }
}

// ---------------------------------------------------------------------------
extern "C" void kernel_launch(void* const* d_in, const int* in_sizes, int n_in,
                              void* d_out, int out_size, void* d_ws, size_t ws_size,
                              hipStream_t stream) {
    const float* x      = (const float*)d_in[0];
    const float* wqkv_h = (const float*)d_in[1];
    const float* wqkv_l = (const float*)d_in[2];
    const float* wproj  = (const float*)d_in[3];
    const float* bproj  = (const float*)d_in[4];
    float* out = (float*)d_out;

    char* ws = (char*)d_ws;
    unsigned short* WH   = (unsigned short*)(ws + 0);         // 1536*512 bf16
    unsigned short* WLV  = (unsigned short*)(ws + 1572864);   // 512*512
    unsigned short* WP1  = (unsigned short*)(ws + 2097152);   // 512*512
    unsigned short* WP2  = (unsigned short*)(ws + 2621440);   // 512*512
    unsigned short* XW   = (unsigned short*)(ws + 3145728);   // 50176*512
    unsigned short* XAVG = (unsigned short*)(ws + 54525952);  // 3136*512
    unsigned short* VL   = (unsigned short*)(ws + 57737216);  // 3136*512
    float*          G    = (float*)(ws + 60948480);           // 3136*512 f32
    unsigned short* XH   = (unsigned short*)(ws + 67371008);  // 50176*512

    k_prep_weights<<<dim3(6144), dim3(256), 0, stream>>>(wqkv_h, wqkv_l, wproj, WH, WLV, WP1, WP2);
    k_window_pool<<<dim3(1568), dim3(256), 0, stream>>>(x, XW, XAVG);
    k_gemm512<2><<<dim3(49, 16), dim3(256), 0, stream>>>(XAVG, WLV, VL, (float*)nullptr, (const float*)nullptr);
    k_gemm512<2><<<dim3(49, 16), dim3(256), 0, stream>>>(VL, WP2, (unsigned short*)nullptr, G, bproj);
    k_fused<<<dim3(784), dim3(256), 0, stream>>>(XW, WH, XH);
    k_gemm_proj<<<dim3(784, 4), dim3(256), 0, stream>>>(XH, WP1, G, out);
}

// Round 2
// 386.630 us; speedup vs baseline: 1.2743x; 1.2743x over previous
//
#include <hip/hip_runtime.h>

// ---------------------------------------------------------------------------
// SpatialAwareSelfAttention  (B=16, H=W=56, C=512, heads=8, window=4x4)
//
// Round 5: back to round-0 grid (784,8) = 6272 blocks (4 blocks/CU, deep
// block queue), with three surgical fixes:
//  1. N-split wave tile for the qkv GEMM: wave = M64 x N48 (4x3 frags) ->
//     7 ds_read_b128 per 12 MFMAs (was 13 per 12). Halves LDS-read load.
//  2. Proven both-sides XOR swizzle (linear gl2lds dest + inverse-swizzled
//     global src + swizzled ds_read): BK=64 rows (128B) -> 2-way = free.
//  3. BK=64 single-buffer chunks: 8 iters x 2 barriers (was 16 x 2).
//  Plus bijective XCD remap (784%8==0): the 8 heads of one token-block run
//  consecutively on one XCD -> A-tile L2 reuse.
//  k_gemm_proj rebuilt the same way: 128x128 block, wave 64x64 (8 reads per
//  16 MFMAs), BK=64, swizzled, XCD remap.
// ---------------------------------------------------------------------------

using bf16x8 = __attribute__((ext_vector_type(8))) short;
using f32x4  = __attribute__((ext_vector_type(4))) float;

#define SCALE 0.044194173824159216f   // 512^-0.5 (full C, per reference)

__device__ __forceinline__ unsigned short f2bf(float f) {
    union { float f; unsigned u; } v; v.f = f;
    unsigned u = v.u;
    return (unsigned short)((u + 0x7fffu + ((u >> 16) & 1u)) >> 16);
}

__device__ __forceinline__ void gl2lds16(const unsigned short* g, unsigned short* l) {
    __builtin_amdgcn_global_load_lds(
        (const __attribute__((address_space(1))) void*)g,
        (__attribute__((address_space(3))) void*)l, 16, 0, 0);
}

// ---- K0a: weight conversion/repack ----------------------------------------
__global__ void k_prep_weights(const float* __restrict__ wqkv_h,
                               const float* __restrict__ wqkv_l,
                               const float* __restrict__ wproj,
                               unsigned short* __restrict__ WH,
                               unsigned short* __restrict__ WLV,
                               unsigned short* __restrict__ WP1,
                               unsigned short* __restrict__ WP2) {
    int i = blockIdx.x * 256 + threadIdx.x;
    if (i < 786432) {
        WH[i] = f2bf(wqkv_h[i]);              // [1536][512] row-major
    } else {
        int j = i - 786432;
        int r = j >> 18;
        int t = j & 262143;
        int n = t >> 9, k = t & 511;
        if (r == 0)      WLV[t] = f2bf(wqkv_l[(1024 + n) * 512 + k]); // v-rows
        else if (r == 1) WP1[t] = f2bf(wproj[n * 1024 + k]);
        else             WP2[t] = f2bf(wproj[n * 1024 + 512 + k]);
    }
}

// ---- K0b: window partition + pooling (float4 / ushort4) -------------------
__global__ void k_window_pool(const float* __restrict__ x,
                              unsigned short* __restrict__ XW,
                              unsigned short* __restrict__ XAVG) {
    int win = blockIdx.x * 2 + (threadIdx.x >> 7);
    int g = threadIdx.x & 127;
    int c = g * 4;
    int b = win / 196, rem = win % 196, wh = rem / 14, ww = rem % 14;
    float4 s = {0.f, 0.f, 0.f, 0.f};
    #pragma unroll
    for (int t = 0; t < 16; ++t) {
        int row = (b * 56 + wh * 4 + (t >> 2)) * 56 + ww * 4 + (t & 3);
        float4 v = *(const float4*)&x[(size_t)row * 512 + c];
        uint2 pk;
        pk.x = (unsigned)f2bf(v.x) | ((unsigned)f2bf(v.y) << 16);
        pk.y = (unsigned)f2bf(v.z) | ((unsigned)f2bf(v.w) << 16);
        *(uint2*)&XW[(size_t)(win * 16 + t) * 512 + c] = pk;
        s.x += v.x; s.y += v.y; s.z += v.z; s.w += v.w;
    }
    uint2 pa;
    pa.x = (unsigned)f2bf(s.x * 0.0625f) | ((unsigned)f2bf(s.y * 0.0625f) << 16);
    pa.y = (unsigned)f2bf(s.z * 0.0625f) | ((unsigned)f2bf(s.w * 0.0625f) << 16);
    *(uint2*)&XAVG[(size_t)win * 512 + c] = pa;
}

// ---- K1: small K=512 GEMM C = A @ B^T, wave tile 16 x (NT*16) -------------
template <int NT>
__global__ void k_gemm512(const unsigned short* __restrict__ A,
                          const unsigned short* __restrict__ Bw,
                          unsigned short* __restrict__ outB,
                          float* __restrict__ outF,
                          const float* __restrict__ bias) {
    int wave = threadIdx.x >> 6, lane = threadIdx.x & 63;
    int quad = lane >> 4, l16 = lane & 15;
    int m0 = blockIdx.x * 64 + wave * 16;
    int n0 = blockIdx.y * (NT * 16);
    f32x4 acc[NT] = {};
    const unsigned short* arow = A + (size_t)(m0 + l16) * 512 + quad * 8;
    for (int kk = 0; kk < 16; ++kk) {
        bf16x8 a = *(const bf16x8*)(arow + kk * 32);
        #pragma unroll
        for (int nt = 0; nt < NT; ++nt) {
            bf16x8 b = *(const bf16x8*)(Bw + (size_t)(n0 + nt * 16 + l16) * 512 + kk * 32 + quad * 8);
            acc[nt] = __builtin_amdgcn_mfma_f32_16x16x32_bf16(a, b, acc[nt], 0, 0, 0);
        }
    }
    #pragma unroll
    for (int nt = 0; nt < NT; ++nt) {
        int col = n0 + nt * 16 + l16;
        float bv = (bias != nullptr) ? bias[col] : 0.f;
        #pragma unroll
        for (int r = 0; r < 4; ++r) {
            int row = m0 + quad * 4 + r;
            if (outF != nullptr) outF[(size_t)row * 512 + col] = acc[nt][r] + bv;
            else                 outB[(size_t)row * 512 + col] = f2bf(acc[nt][r]);
        }
    }
}

// ---- K2: fused qkv GEMM (64x192x512) + window attention -------------------
// grid (784, 8) remapped so the 8 heads of a token-block run consecutively
// on one XCD. Wave tile: M=64 (all tokens) x N=48 (12-col split of q|k|v).
__global__ void __launch_bounds__(256, 4) k_fused(const unsigned short* __restrict__ XW,
                                                  const unsigned short* __restrict__ WH,
                                                  unsigned short* __restrict__ XH) {
    __shared__ __align__(16) char smem[33792];
    // staging region (dead after K-loop):
    unsigned short* As  = (unsigned short*)smem;             // [64][64]   8192 B
    unsigned short* Bs  = (unsigned short*)(smem + 8192);    // [192][64] 24576 B
    // attention region (aliases staging, used after K-loop):
    unsigned short* qs  = (unsigned short*)smem;             // [64][72]   9216 B
    unsigned short* ks  = (unsigned short*)(smem + 9216);    // [64][72]   9216 B
    unsigned short* vts = (unsigned short*)(smem + 18432);   // [64][88]  11264 B (ch x tok)
    unsigned short* Ps  = (unsigned short*)(smem + 29696);   // [4][16][32] 4096 B

    const int wave = threadIdx.x >> 6, lane = threadIdx.x & 63;
    const int quad = lane >> 4, l16 = lane & 15;

    // bijective XCD remap (6272 = 8*784, dispatch id % 8 = XCD):
    // XCD c handles token-blocks [c*98, c*98+98), heads cycling fastest.
    int id  = blockIdx.y * 784 + blockIdx.x;
    int s   = id >> 3;
    int tb  = (id & 7) * 98 + (s >> 3);
    int head = s & 7;
    const int m0 = tb * 64;
    const int t0 = wave * 16;
    const unsigned short* Bh = WH + head * 32768;   // head panel base

    // staging maps (rule #21: linear LDS dest, inverse-swizzled global src,
    // swizzled ds_read; 128B rows -> 8 16B-units, unit u holds g-unit u^(n&7))
    int aofs[2], bofs[6];
    #pragma unroll
    for (int i = 0; i < 2; ++i) {
        int u = (wave * 2 + i) * 64 + lane;        // A unit 0..511
        int n = u >> 3;                            // A row 0..63
        int gu = (lane & 7) ^ (n & 7);
        aofs[i] = (m0 + n) * 512 + gu * 8;
    }
    #pragma unroll
    for (int i = 0; i < 6; ++i) {
        int u = (wave * 6 + i) * 64 + lane;        // B unit 0..1535
        int n = u >> 3;                            // qkv row 0..191 (s-major)
        int gu = (lane & 7) ^ (n & 7);
        int nrow = (n >> 6) * 512 + (n & 63);      // q/k/v sections stride 512
        bofs[i] = nrow * 512 + gu * 8;
    }

    f32x4 acc[4][3] = {};    // [Mfrag][Nfrag]: rows mf*16+, cols wave*48+j*16+
    const int sx = l16 & 7;

    for (int ch = 0; ch < 8; ++ch) {               // K chunks of 64
        #pragma unroll
        for (int i = 0; i < 2; ++i)
            gl2lds16(XW + aofs[i] + ch * 64, As + (wave * 2 + i) * 512);
        #pragma unroll
        for (int i = 0; i < 6; ++i)
            gl2lds16(Bh + bofs[i] + ch * 64, Bs + (wave * 6 + i) * 512);
        __syncthreads();
        #pragma unroll
        for (int kk = 0; kk < 2; ++kk) {
            int su = ((kk * 4 + quad) ^ sx) * 8;
            bf16x8 a[4], b[3];
            #pragma unroll
            for (int mf = 0; mf < 4; ++mf)
                a[mf] = *(const bf16x8*)&As[(mf * 16 + l16) * 64 + su];
            #pragma unroll
            for (int j = 0; j < 3; ++j)
                b[j] = *(const bf16x8*)&Bs[(wave * 48 + j * 16 + l16) * 64 + su];
            #pragma unroll
            for (int mf = 0; mf < 4; ++mf)
                #pragma unroll
                for (int j = 0; j < 3; ++j)
                    acc[mf][j] = __builtin_amdgcn_mfma_f32_16x16x32_bf16(a[mf], b[j], acc[mf][j], 0, 0, 0);
        }
        __syncthreads();
    }

    // ---- scatter q/k/v^T into attention LDS (aliases staging) -------------
    // wave owns cols wave*48 + j*16 + l16 of the 64x192 output.
    #pragma unroll
    for (int j = 0; j < 3; ++j) {
        int cb = wave * 48 + j * 16;               // uniform, 16-aligned
        #pragma unroll
        for (int mf = 0; mf < 4; ++mf) {
            #pragma unroll
            for (int r = 0; r < 4; ++r) {
                int tok = mf * 16 + quad * 4 + r;
                unsigned short hv = f2bf(acc[mf][j][r]);
                if (cb < 64)       qs[tok * 72 + cb + l16] = hv;
                else if (cb < 128) ks[tok * 72 + (cb - 64) + l16] = hv;
                else               vts[(cb - 128 + l16) * 88 + tok] = hv;
            }
        }
    }
    __syncthreads();   // waves no longer own their window's columns

    // re-zero pads (staging clobbered them; consumers are wave-local):
    // vts token-cols 64..79 (wave 3's PV K-pad), Ps cols 16..31.
    if (wave == 3) {
        #pragma unroll
        for (int i = 0; i < 16; ++i) vts[lane * 88 + 64 + i] = 0;
    }
    {
        int prow = lane >> 2, pc = 16 + (lane & 3) * 4;
        #pragma unroll
        for (int i = 0; i < 4; ++i) Ps[wave * 512 + prow * 32 + pc + i] = 0;
    }

    // ---- S = (q @ k^T) * scale --------------------------------------------
    f32x4 sacc = {};
    {
        bf16x8 a0 = *(const bf16x8*)&qs[(t0 + l16) * 72 + quad * 8];
        bf16x8 b0 = *(const bf16x8*)&ks[(t0 + l16) * 72 + quad * 8];
        sacc = __builtin_amdgcn_mfma_f32_16x16x32_bf16(a0, b0, sacc, 0, 0, 0);
        bf16x8 a1 = *(const bf16x8*)&qs[(t0 + l16) * 72 + 32 + quad * 8];
        bf16x8 b1 = *(const bf16x8*)&ks[(t0 + l16) * 72 + 32 + quad * 8];
        sacc = __builtin_amdgcn_mfma_f32_16x16x32_bf16(a1, b1, sacc, 0, 0, 0);
    }
    // ---- in-register softmax: row r lives across the quad's 16 lanes ------
    float p[4];
    #pragma unroll
    for (int r = 0; r < 4; ++r) {
        float v = sacc[r] * SCALE;
        float m = v;
        m = fmaxf(m, __shfl_xor(m, 1));
        m = fmaxf(m, __shfl_xor(m, 2));
        m = fmaxf(m, __shfl_xor(m, 4));
        m = fmaxf(m, __shfl_xor(m, 8));
        float e = __expf(v - m);
        float sm = e;
        sm += __shfl_xor(sm, 1);
        sm += __shfl_xor(sm, 2);
        sm += __shfl_xor(sm, 4);
        sm += __shfl_xor(sm, 8);
        p[r] = e / sm;
    }
    #pragma unroll
    for (int r = 0; r < 4; ++r)
        Ps[wave * 512 + (quad * 4 + r) * 32 + l16] = f2bf(p[r]);

    // ---- y = P @ v (K=16 padded to 32; pad-P is zero) ---------------------
    bf16x8 pa = *(const bf16x8*)&Ps[wave * 512 + l16 * 32 + quad * 8];
    #pragma unroll
    for (int nt = 0; nt < 4; ++nt) {
        f32x4 y = {};
        bf16x8 bv = *(const bf16x8*)&vts[(nt * 16 + l16) * 88 + t0 + quad * 8];
        y = __builtin_amdgcn_mfma_f32_16x16x32_bf16(pa, bv, y, 0, 0, 0);
        #pragma unroll
        for (int r = 0; r < 4; ++r)
            XH[(size_t)(m0 + t0 + quad * 4 + r) * 512 + head * 64 + nt * 16 + l16] = f2bf(y[r]);
    }
}

// ---- K3: out = XH @ WP1^T + G[win], 128x128 block, wave 64x64 -------------
// grid (392, 4), XCD-remapped; BK=64 swizzled staging.
__global__ void __launch_bounds__(256, 3) k_gemm_proj(const unsigned short* __restrict__ XH,
                                                      const unsigned short* __restrict__ WP1,
                                                      const float* __restrict__ G,
                                                      float* __restrict__ out) {
    __shared__ __align__(16) unsigned short As[8192];   // [128][64]  16 KB
    __shared__ __align__(16) unsigned short Bs[8192];   // [128][64]  16 KB

    const int wave = threadIdx.x >> 6, lane = threadIdx.x & 63;
    const int quad = lane >> 4, l16 = lane & 15;

    // bijective XCD remap (1568 = 8*196): 4 col-blocks of one row-block
    // run consecutively on one XCD -> XH tile L2 reuse.
    int id = blockIdx.y * 392 + blockIdx.x;
    int s  = id >> 3;
    int xb = (id & 7) * 49 + (s >> 2);
    int yb = s & 3;
    const int m0 = xb * 128, n0 = yb * 128;
    const int wm = (wave >> 1) * 64;   // wave row offset (2x2 wave grid)
    const int wn = (wave & 1) * 64;    // wave col offset

    int aofs[4], bofs[4];
    #pragma unroll
    for (int i = 0; i < 4; ++i) {
        int u = (wave * 4 + i) * 64 + lane;   // unit 0..1023
        int n = u >> 3;                        // row 0..127
        int gu = (lane & 7) ^ (n & 7);
        aofs[i] = (m0 + n) * 512 + gu * 8;
        bofs[i] = (n0 + n) * 512 + gu * 8;
    }

    f32x4 acc[4][4] = {};
    const int sx = l16 & 7;

    for (int ch = 0; ch < 8; ++ch) {
        #pragma unroll
        for (int i = 0; i < 4; ++i) {
            gl2lds16(XH + aofs[i] + ch * 64, As + (wave * 4 + i) * 512);
            gl2lds16(WP1 + bofs[i] + ch * 64, Bs + (wave * 4 + i) * 512);
        }
        __syncthreads();
        #pragma unroll
        for (int kk = 0; kk < 2; ++kk) {
            int su = ((kk * 4 + quad) ^ sx) * 8;
            bf16x8 a[4], b[4];
            #pragma unroll
            for (int mf = 0; mf < 4; ++mf)
                a[mf] = *(const bf16x8*)&As[(wm + mf * 16 + l16) * 64 + su];
            #pragma unroll
            for (int j = 0; j < 4; ++j)
                b[j] = *(const bf16x8*)&Bs[(wn + j * 16 + l16) * 64 + su];
            #pragma unroll
            for (int mf = 0; mf < 4; ++mf)
                #pragma unroll
                for (int j = 0; j < 4; ++j)
                    acc[mf][j] = __builtin_amdgcn_mfma_f32_16x16x32_bf16(a[mf], b[j], acc[mf][j], 0, 0, 0);
        }
        __syncthreads();
    }

    #pragma unroll
    for (int mf = 0; mf < 4; ++mf) {
        #pragma unroll
        for (int r = 0; r < 4; ++r) {
            int tl  = wm + mf * 16 + quad * 4 + r;   // 0..127
            int gt  = m0 + tl;                        // global token
            int win = gt >> 4, tw = gt & 15;
            int bb = win / 196, rem = win % 196;
            int wh = rem / 14, ww = rem % 14;
            int orow = (bb * 56 + wh * 4 + (tw >> 2)) * 56 + ww * 4 + (tw & 3);
            #pragma unroll
            for (int j = 0; j < 4; ++j) {
                int ncol = n0 + wn + j * 16 + l16;
                out[(size_t)orow * 512 + ncol] = acc[mf][j][r] + G[(size_t)win * 512 + ncol];
            }
        }
    }
}

// ---------------------------------------------------------------------------
extern "C" void kernel_launch(void* const* d_in, const int* in_sizes, int n_in,
                              void* d_out, int out_size, void* d_ws, size_t ws_size,
                              hipStream_t stream) {
    const float* x      = (const float*)d_in[0];
    const float* wqkv_h = (const float*)d_in[1];
    const float* wqkv_l = (const float*)d_in[2];
    const float* wproj  = (const float*)d_in[3];
    const float* bproj  = (const float*)d_in[4];
    float* out = (float*)d_out;

    char* ws = (char*)d_ws;
    unsigned short* WH   = (unsigned short*)(ws + 0);         // 1536*512 bf16
    unsigned short* WLV  = (unsigned short*)(ws + 1572864);   // 512*512
    unsigned short* WP1  = (unsigned short*)(ws + 2097152);   // 512*512
    unsigned short* WP2  = (unsigned short*)(ws + 2621440);   // 512*512
    unsigned short* XW   = (unsigned short*)(ws + 3145728);   // 50176*512
    unsigned short* XAVG = (unsigned short*)(ws + 54525952);  // 3136*512
    unsigned short* VL   = (unsigned short*)(ws + 57737216);  // 3136*512
    float*          G    = (float*)(ws + 60948480);           // 3136*512 f32
    unsigned short* XH   = (unsigned short*)(ws + 67371008);  // 50176*512

    k_prep_weights<<<dim3(6144), dim3(256), 0, stream>>>(wqkv_h, wqkv_l, wproj, WH, WLV, WP1, WP2);
    k_window_pool<<<dim3(1568), dim3(256), 0, stream>>>(x, XW, XAVG);
    k_gemm512<2><<<dim3(49, 16), dim3(256), 0, stream>>>(XAVG, WLV, VL, (float*)nullptr, (const float*)nullptr);
    k_gemm512<2><<<dim3(49, 16), dim3(256), 0, stream>>>(VL, WP2, (unsigned short*)nullptr, G, bproj);
    k_fused<<<dim3(784, 8), dim3(256), 0, stream>>>(XW, WH, XH);
    k_gemm_proj<<<dim3(392, 4), dim3(256), 0, stream>>>(XH, WP1, G, out);
}